// Round 3
// baseline (131.440 us; speedup 1.0000x reference)
//
#include <hip/hip_runtime.h>

// RepulsionLoss: points [B=4, N=8192, 3] fp32 -> scalar.
// Round 11: CSR grid build (unchanged) + FENCED MLP-batched streaming query.
//   R10 post-mortem: VGPR_Count=36 proves the compiler sank the 8-deep load
//   batch back into serial load->insert pairs (8 float4 in flight needs >=32
//   VGPRs for data alone). Fix: __builtin_amdgcn_sched_barrier(0) fences
//   around the load phase -- nothing may cross, so all 8 global_load_dwordx4
//   issue before the first consume (true MLP depth 8). Remainder loop removed
//   via clamp+predication so every candidate runs through the batched path.
//   Verification hook: VGPR must jump to ~80-100, else the fence failed.

#define B_    4
#define N_    8192
#define KNN_  8
#define G_    12
#define C_    (G_ * G_ * G_)   // 1728
#define CS_   (C_ + 1)
#define L_    4                // lanes per point
#define D_    8                // loads in flight per lane (chunk depth)

constexpr float GF_     = (float)G_;
constexpr float CELL_   = 1.0f / GF_;
constexpr float RADIUS_ = 0.07f;
constexpr float INV_H2_ = 1.0f / (0.03f * 0.03f);
constexpr float SCALE_  = 0.1f / (float)(B_ * N_ * KNN_);   // ALPHA / (B*N*K)

__device__ __forceinline__ int cell_coord(float x) {
    int c = (int)(x * GF_);
    return min(max(c, 0), G_ - 1);
}

__device__ __forceinline__ void insert8(float (&t)[KNN_], float v) {
#pragma unroll
    for (int k = 0; k < KNN_; k++) {
        const float lo = fminf(t[k], v);
        v = fmaxf(t[k], v);
        t[k] = lo;
    }
}

// One bitonic merge stage across lane pairs (xor dist): both lanes end with
// the sorted min-8 of the union of their two sorted lists. Valid for disjoint
// candidate multisets.
__device__ __forceinline__ void merge_pair(float (&t)[KNN_], const int dist) {
    float u[KNN_];
#pragma unroll
    for (int i2 = 0; i2 < KNN_; i2++)
        u[i2] = fminf(t[i2], __shfl_xor(t[KNN_ - 1 - i2], dist));
#pragma unroll
    for (int d = 4; d >= 1; d >>= 1) {
#pragma unroll
        for (int i2 = 0; i2 < KNN_; i2++) {
            if ((i2 & d) == 0) {
                const float a = u[i2], e = u[i2 + d];
                u[i2] = fminf(a, e); u[i2 + d] = fmaxf(a, e);
            }
        }
    }
#pragma unroll
    for (int i2 = 0; i2 < KNN_; i2++) t[i2] = u[i2];
}

// Fallback row scan: one lane owns the whole contiguous span; loads within
// the row are independent -> pipeline via unroll.
__device__ __forceinline__ void scan_row(const float4* __restrict__ sp,
                                         int j0, int j1,
                                         float px, float py, float pz,
                                         float (&t)[KNN_]) {
#pragma unroll 2
    for (int j = j0; j < j1; ++j) {
        const float4 Q = sp[j];
        const float dx = px - Q.x, dy = py - Q.y, dz = pz - Q.z;
        const float d2 = dx * dx + dy * dy + dz * dz;
        if (d2 < t[KNN_ - 1]) insert8(t, d2);
    }
}

__global__ __launch_bounds__(256) void count_kernel(const float* __restrict__ pts,
                                                    int* __restrict__ counts,
                                                    float* __restrict__ out) {
    const int g = blockIdx.x * 256 + threadIdx.x;   // 0..B*N-1
    if (g == 0) out[0] = 0.0f;                      // out re-poisoned each replay
    const int b = g >> 13;
    const float x = pts[g * 3 + 0], y = pts[g * 3 + 1], z = pts[g * 3 + 2];
    const int id = (cell_coord(z) * G_ + cell_coord(y)) * G_ + cell_coord(x);
    atomicAdd(&counts[b * C_ + id], 1);
}

// 4 blocks (one per batch): 7 cells/thread, shfl wave-scan + 4 wave partials.
__global__ __launch_bounds__(256) void scan_kernel(const int* __restrict__ counts,
                                                   int* __restrict__ cellStart,
                                                   int* __restrict__ cursor) {
    __shared__ int wsum[4];
    const int b = blockIdx.x, t = threadIdx.x;
    const int lane = t & 63, w = t >> 6;
    const int* cnt = counts + b * C_;
    int vals[7], tot = 0;
    const int c0 = t * 7;                            // 256*7 = 1792 >= 1728
#pragma unroll
    for (int k = 0; k < 7; k++) {
        const int c = c0 + k;
        const int v = (c < C_) ? cnt[c] : 0;
        vals[k] = v; tot += v;
    }
    int incl = tot;
#pragma unroll
    for (int off = 1; off < 64; off <<= 1) {
        const int v = __shfl_up(incl, off, 64);
        if (lane >= off) incl += v;
    }
    if (lane == 63) wsum[w] = incl;
    __syncthreads();
    int woff = 0;
    for (int ww = 0; ww < w; ww++) woff += wsum[ww];
    int run = woff + incl - tot;                     // exclusive base
#pragma unroll
    for (int k = 0; k < 7; k++) {
        const int c = c0 + k;
        if (c < C_) {
            cellStart[b * CS_ + c] = run;
            cursor[b * C_ + c]     = run;
            run += vals[k];
        }
    }
    if (t == 255) cellStart[b * CS_ + C_] = N_;
}

__global__ __launch_bounds__(256) void scatter_kernel(const float* __restrict__ pts,
                                                      int* __restrict__ cursor,
                                                      float4* __restrict__ sorted4) {
    const int g = blockIdx.x * 256 + threadIdx.x;
    const int b = g >> 13;
    const float x = pts[g * 3 + 0], y = pts[g * 3 + 1], z = pts[g * 3 + 2];
    const int id = (cell_coord(z) * G_ + cell_coord(y)) * G_ + cell_coord(x);
    const int pos = atomicAdd(&cursor[b * C_ + id], 1);
    sorted4[(size_t)b * N_ + pos] = make_float4(x, y, z, 0.0f);
}

// 512 blocks x 256 threads: 64 sorted points/block, 4 lanes/point.
__global__ __launch_bounds__(256) void query_kernel(const float4* __restrict__ sorted4,
                                                    const int* __restrict__ cellStart,
                                                    float* __restrict__ out) {
    __shared__ float bsum[4];
    const int tid = threadIdx.x;
    const int b   = blockIdx.x >> 7;                         // 128 blocks/batch
    const int i   = ((blockIdx.x & 127) << 6) + (tid >> 2);  // sorted index
    const int l   = tid & 3;                                 // lane within point

    const int*    csg = cellStart + b * CS_;
    const float4* sp  = sorted4 + (size_t)b * N_;
    const float4 P = sp[i];
    const float px = P.x, py = P.y, pz = P.z;
    const int cx = cell_coord(px), cy = cell_coord(py), cz = cell_coord(pz);

    // Rings 0+1 as 9 raster-contiguous x-rows, concatenated into one virtual
    // stream. O[n] = prefix candidate count, A[n] = addr base - prefix, so
    // candidate c lives at sp[c + A[n(c)]]. All registers, static indexing.
    const int xa = max(cx - 1, 0), xb = min(cx + 1, G_ - 1);
    int O[10], A[9];
    O[0] = 0;
#pragma unroll
    for (int n = 0; n < 9; n++) {
        const int dz = n / 3 - 1, dy = n % 3 - 1;   // compile-time per unroll
        const int z = cz + dz, y = cy + dy;
        int j0 = 0, j1 = 0;
        if ((unsigned)z < G_ && (unsigned)y < G_) {
            const int rb = (z * G_ + y) * G_;
            j0 = csg[rb + xa]; j1 = csg[rb + xb + 1];
        }
        O[n + 1] = O[n] + (j1 - j0);
        A[n]     = j0 - O[n];
    }
    const int tot = O[9];

    float t[KNN_];
#pragma unroll
    for (int k = 0; k < KNN_; k++) t[k] = 1e30f;

    // MLP-batched main loop, FENCED so the compiler cannot sink the loads:
    // phase 1: 8 independent address select-chains (pure VALU, pipelined)
    // phase 2: 8 global_load_dwordx4 issued back-to-back (all in flight)
    // phase 3: distance + conditional insert (drains vmcnt 7..0)
    // Tail handled by clamp + predication (no serialized remainder loop).
    for (int cb = 0; cb < tot; cb += L_ * D_) {
        int addr[D_], live[D_];
#pragma unroll
        for (int k = 0; k < D_; k++) {
            const int c = cb + (k << 2) + l;
            live[k] = (c < tot);
            const int cc = min(c, tot - 1);
            int a = A[0];
#pragma unroll
            for (int n = 1; n < 9; n++) a = (cc >= O[n]) ? A[n] : a;
            addr[k] = cc + a;
        }
        __builtin_amdgcn_sched_barrier(0);
        float4 Q[D_];
#pragma unroll
        for (int k = 0; k < D_; k++) Q[k] = sp[addr[k]];
        __builtin_amdgcn_sched_barrier(0);
#pragma unroll
        for (int k = 0; k < D_; k++) {
            const float dx = px - Q[k].x, dy = py - Q[k].y, dz = pz - Q[k].z;
            const float d2 = dx * dx + dy * dy + dz * dz;
            if (live[k] && d2 < t[KNN_ - 1]) insert8(t, d2);
        }
    }

    // True merged 8th-NN bound via temp copy (t stays disjoint slices).
    float m;
    {
        float tmp[KNN_];
#pragma unroll
        for (int k = 0; k < KNN_; k++) tmp[k] = t[k];
        merge_pair(tmp, 1); merge_pair(tmp, 2);
        m = tmp[KNN_ - 1];
    }

    // Exact fallback: ring r while ((r-1)*g)^2 < m. Rows round-robined across
    // the point's 4 lanes; each lane scans its full contiguous span (pipelined
    // loads). Each candidate visited by exactly one lane -> lists stay disjoint.
    for (int r = 2; r < G_; r++) {
        const float dmin = (float)(r - 1) * CELL_;
        if (dmin * dmin >= m) break;
        int nrow = 0;
        for (int dz = -r; dz <= r; ++dz) {
            const int z = cz + dz; if ((unsigned)z >= G_) continue;
            const bool zface = (dz == -r) | (dz == r);
            for (int dy = -r; dy <= r; ++dy) {
                const int y = cy + dy; if ((unsigned)y >= G_) continue;
                const int rb = (z * G_ + y) * G_;
                if (zface | (dy == -r) | (dy == r)) {
                    if ((nrow++ & (L_ - 1)) == l) {
                        const int x0 = max(cx - r, 0), x1 = min(cx + r, G_ - 1);
                        scan_row(sp, csg[rb + x0], csg[rb + x1 + 1], px, py, pz, t);
                    }
                } else {
                    const int xm = cx - r, xp = cx + r;
                    if (xm >= 0) {
                        if ((nrow++ & (L_ - 1)) == l)
                            scan_row(sp, csg[rb + xm], csg[rb + xm + 1], px, py, pz, t);
                    }
                    if (xp < G_) {
                        if ((nrow++ & (L_ - 1)) == l)
                            scan_row(sp, csg[rb + xp], csg[rb + xp + 1], px, py, pz, t);
                    }
                }
            }
        }
        // Valid upper bound: union 8th <= min over lanes of per-lane 8th.
        float e = t[KNN_ - 1];
        e = fminf(e, __shfl_xor(e, 1));
        e = fminf(e, __shfl_xor(e, 2));
        m = fminf(m, e);
    }

    // Final exact top-8 of the 4 disjoint lane lists.
    merge_pair(t, 1); merge_pair(t, 2);

    float tsum = 0.0f;
    if (l == 0) {
#pragma unroll
        for (int k = 0; k < KNN_; k++) {
            const float dm = fmaxf(t[k], 1e-12f);   // self: d2=0 -> dn=1e-6
            const float dn = sqrtf(dm);
            tsum += (RADIUS_ - dn) * __expf(-dm * INV_H2_);
        }
    }
#pragma unroll
    for (int off = 1; off < 64; off <<= 1) tsum += __shfl_xor(tsum, off);
    if ((tid & 63) == 0) bsum[tid >> 6] = tsum;
    __syncthreads();
    if (tid == 0)
        atomicAdd(out, (bsum[0] + bsum[1] + bsum[2] + bsum[3]) * SCALE_);
}

extern "C" void kernel_launch(void* const* d_in, const int* in_sizes, int n_in,
                              void* d_out, int out_size, void* d_ws, size_t ws_size,
                              hipStream_t stream) {
    const float* pts = (const float*)d_in[0];
    float*       out = (float*)d_out;

    char* ws = (char*)d_ws;
    float4* sorted4   = (float4*)(ws);                            // 524288 B
    int*    counts    = (int*)(ws + 524288);                      //  27648 B
    int*    cellStart = (int*)(ws + 524288 + 27648);              //  27664 B
    int*    cursor    = (int*)(ws + 524288 + 27648 + 27664);      //  27648 B

    hipMemsetAsync(counts, 0, B_ * C_ * sizeof(int), stream);
    count_kernel  <<<B_ * N_ / 256, 256, 0, stream>>>(pts, counts, out);
    scan_kernel   <<<B_,            256, 0, stream>>>(counts, cellStart, cursor);
    scatter_kernel<<<B_ * N_ / 256, 256, 0, stream>>>(pts, cursor, sorted4);
    query_kernel  <<<B_ * N_ / 64,  256, 0, stream>>>(sorted4, cellStart, out);
}

// Round 4
// 107.596 us; speedup vs baseline: 1.2216x; 1.2216x over previous
//
#include <hip/hip_runtime.h>

// RepulsionLoss: points [B=4, N=8192, 3] fp32 -> scalar.
// Round 12: CSR grid build (unchanged) + LDS-SLAB query.
//   R9-R11 post-mortem: wave count, lane split, and sched_barrier fences all
//   failed to move 63-73us because the cost is the DIVERGENT ring-2 fallback:
//   ~35% of points (near box faces) need ring 2, so nearly every wave pays a
//   serialized 98-row walk of dependent global loads (~40us). Fix the latency
//   itself: points are cell-sorted, so a block's 128 points + their full
//   ring-2 reach live in <=6 z-planes (<=4608 pts, 11-sigma cap). Stage those
//   planes (one contiguous coalesced span) + cellStart slice into LDS; main
//   loop AND ring-2 then read ~few-cycle LDS. Ring >=3 (8th-NN > 2 cells,
//   rare corner tail) keeps the exact global-memory path.
//   Hooks: LDS_Block_Size ~77KB, query ~8-16us. 77KB static LDS is legal on
//   gfx950 (guide m201 example uses 128KB).

#define B_    4
#define N_    8192
#define KNN_  8
#define G_    12
#define C_    (G_ * G_ * G_)   // 1728
#define CS_   (C_ + 1)
#define PLANE_ (G_ * G_)       // 144
#define SLAB_CAP 4608          // float4 slots: 6 planes avg 4096, sd ~45
#define CS_CAP   (6 * PLANE_ + 1)  // 865

constexpr float GF_     = (float)G_;
constexpr float CELL_   = 1.0f / GF_;
constexpr float RADIUS_ = 0.07f;
constexpr float INV_H2_ = 1.0f / (0.03f * 0.03f);
constexpr float SCALE_  = 0.1f / (float)(B_ * N_ * KNN_);   // ALPHA / (B*N*K)

__device__ __forceinline__ int cell_coord(float x) {
    int c = (int)(x * GF_);
    return min(max(c, 0), G_ - 1);
}

__device__ __forceinline__ void insert8(float (&t)[KNN_], float v) {
#pragma unroll
    for (int k = 0; k < KNN_; k++) {
        const float lo = fminf(t[k], v);
        v = fmaxf(t[k], v);
        t[k] = lo;
    }
}

// One bitonic merge stage across lane pairs (xor dist): both lanes end with
// the sorted min-8 of the union of their two sorted lists. Valid for disjoint
// candidate multisets.
__device__ __forceinline__ void merge_pair(float (&t)[KNN_], const int dist) {
    float u[KNN_];
#pragma unroll
    for (int i2 = 0; i2 < KNN_; i2++)
        u[i2] = fminf(t[i2], __shfl_xor(t[KNN_ - 1 - i2], dist));
#pragma unroll
    for (int d = 4; d >= 1; d >>= 1) {
#pragma unroll
        for (int i2 = 0; i2 < KNN_; i2++) {
            if ((i2 & d) == 0) {
                const float a = u[i2], e = u[i2 + d];
                u[i2] = fminf(a, e); u[i2 + d] = fmaxf(a, e);
            }
        }
    }
#pragma unroll
    for (int i2 = 0; i2 < KNN_; i2++) t[i2] = u[i2];
}

// Span scan from the LDS slab (slab-local indices), 2-way lane split.
__device__ __forceinline__ void scan_lds(const float4 (&sl)[SLAB_CAP],
                                         int j0, int j1, int s,
                                         float px, float py, float pz,
                                         float (&t)[KNN_]) {
    for (int j = j0 + s; j < j1; j += 2) {
        const float4 Q = sl[j];
        const float dx = px - Q.x, dy = py - Q.y, dz = pz - Q.z;
        const float d2 = dx * dx + dy * dy + dz * dz;
        if (d2 < t[KNN_ - 1]) insert8(t, d2);
    }
}

// Span scan from global memory (ring >=3 only, rare).
__device__ __forceinline__ void scan_glb(const float4* __restrict__ sp,
                                         int j0, int j1, int s,
                                         float px, float py, float pz,
                                         float (&t)[KNN_]) {
    for (int j = j0 + s; j < j1; j += 2) {
        const float4 Q = sp[j];
        const float dx = px - Q.x, dy = py - Q.y, dz = pz - Q.z;
        const float d2 = dx * dx + dy * dy + dz * dz;
        if (d2 < t[KNN_ - 1]) insert8(t, d2);
    }
}

__global__ __launch_bounds__(256) void count_kernel(const float* __restrict__ pts,
                                                    int* __restrict__ counts,
                                                    float* __restrict__ out) {
    const int g = blockIdx.x * 256 + threadIdx.x;   // 0..B*N-1
    if (g == 0) out[0] = 0.0f;                      // out re-poisoned each replay
    const int b = g >> 13;
    const float x = pts[g * 3 + 0], y = pts[g * 3 + 1], z = pts[g * 3 + 2];
    const int id = (cell_coord(z) * G_ + cell_coord(y)) * G_ + cell_coord(x);
    atomicAdd(&counts[b * C_ + id], 1);
}

// 4 blocks (one per batch): 7 cells/thread, shfl wave-scan + 4 wave partials.
__global__ __launch_bounds__(256) void scan_kernel(const int* __restrict__ counts,
                                                   int* __restrict__ cellStart,
                                                   int* __restrict__ cursor) {
    __shared__ int wsum[4];
    const int b = blockIdx.x, t = threadIdx.x;
    const int lane = t & 63, w = t >> 6;
    const int* cnt = counts + b * C_;
    int vals[7], tot = 0;
    const int c0 = t * 7;                            // 256*7 = 1792 >= 1728
#pragma unroll
    for (int k = 0; k < 7; k++) {
        const int c = c0 + k;
        const int v = (c < C_) ? cnt[c] : 0;
        vals[k] = v; tot += v;
    }
    int incl = tot;
#pragma unroll
    for (int off = 1; off < 64; off <<= 1) {
        const int v = __shfl_up(incl, off, 64);
        if (lane >= off) incl += v;
    }
    if (lane == 63) wsum[w] = incl;
    __syncthreads();
    int woff = 0;
    for (int ww = 0; ww < w; ww++) woff += wsum[ww];
    int run = woff + incl - tot;                     // exclusive base
#pragma unroll
    for (int k = 0; k < 7; k++) {
        const int c = c0 + k;
        if (c < C_) {
            cellStart[b * CS_ + c] = run;
            cursor[b * C_ + c]     = run;
            run += vals[k];
        }
    }
    if (t == 255) cellStart[b * CS_ + C_] = N_;
}

__global__ __launch_bounds__(256) void scatter_kernel(const float* __restrict__ pts,
                                                      int* __restrict__ cursor,
                                                      float4* __restrict__ sorted4) {
    const int g = blockIdx.x * 256 + threadIdx.x;
    const int b = g >> 13;
    const float x = pts[g * 3 + 0], y = pts[g * 3 + 1], z = pts[g * 3 + 2];
    const int id = (cell_coord(z) * G_ + cell_coord(y)) * G_ + cell_coord(x);
    const int pos = atomicAdd(&cursor[b * C_ + id], 1);
    sorted4[(size_t)b * N_ + pos] = make_float4(x, y, z, 0.0f);
}

// 256 blocks x 256 threads: 128 sorted points/block, 2 lanes/point.
__global__ __launch_bounds__(256) void query_kernel(const float4* __restrict__ sorted4,
                                                    const int* __restrict__ cellStart,
                                                    float* __restrict__ out) {
    __shared__ float4 slab[SLAB_CAP];
    __shared__ int    scs[CS_CAP];

    const int tid  = threadIdx.x;
    const int b    = blockIdx.x >> 6;                  // 64 blocks/batch
    const int base = (blockIdx.x & 63) << 7;           // first point of block
    const int i    = base + (tid >> 1);                // this thread's point
    const int s    = tid & 1;                          // lane within point

    const int*    csg = cellStart + b * CS_;
    const float4* sp  = sorted4 + (size_t)b * N_;

    // Slab bounds (uniform): block's points are cell-sorted, so all ring<=2
    // reach lies in z-planes [zf-2, zl+2] (<=6 planes, SLAB_CAP is ~11 sigma).
    const int zf  = cell_coord(sp[base].z);
    const int zl  = cell_coord(sp[base + 127].z);
    const int zlo = max(zf - 2, 0), zhi = min(zl + 2, G_ - 1);
    const int cs0 = zlo * PLANE_;
    const int cs1 = (zhi + 1) * PLANE_;                // <= C_
    const int start = csg[cs0];
    const int cnt   = csg[cs1] - start;
    const int csn   = cs1 - cs0 + 1;
    for (int k = tid; k < csn; k += 256) scs[k]  = csg[cs0 + k];
    for (int k = tid; k < cnt; k += 256) slab[k] = sp[start + k];
    __syncthreads();

    const float4 P = slab[i - start];
    const float px = P.x, py = P.y, pz = P.z;
    const int cx = cell_coord(px), cy = cell_coord(py), cz = cell_coord(pz);

    // Rings 0+1: 9 raster-contiguous x-rows, bounds from LDS cellStart slice,
    // points from LDS slab (slab-local indices).
    const int xa = max(cx - 1, 0), xb = min(cx + 1, G_ - 1);
    int j0[9], j1[9];
#pragma unroll
    for (int n = 0; n < 9; n++) {
        const int dz = n / 3 - 1, dy = n % 3 - 1;
        const int z = cz + dz, y = cy + dy;
        if ((unsigned)z < G_ && (unsigned)y < G_) {
            const int rb = (z * G_ + y) * G_ - cs0;
            j0[n] = scs[rb + xa] - start;
            j1[n] = scs[rb + xb + 1] - start;
        } else { j0[n] = 0; j1[n] = 0; }
    }

    float t[KNN_];
#pragma unroll
    for (int k = 0; k < KNN_; k++) t[k] = 1e30f;

#pragma unroll
    for (int n = 0; n < 9; n++)
        scan_lds(slab, j0[n], j1[n], s, px, py, pz, t);

    // True merged 8th-NN bound via temp copy (t stays disjoint slices).
    float m;
    {
        float tmp[KNN_];
#pragma unroll
        for (int k = 0; k < KNN_; k++) tmp[k] = t[k];
        merge_pair(tmp, 1);
        m = tmp[KNN_ - 1];
    }

    // Exact fallback: ring r while ((r-1)*g)^2 < m. r==2 reads LDS (staged);
    // r>=3 (8th-NN > 2 cells: rare corner tail) reads global. Skipped
    // candidate d2 >= dmin^2 >= m and 8 union values <= m already held.
    for (int r = 2; r < G_; r++) {
        const float dmin = (float)(r - 1) * CELL_;
        if (dmin * dmin >= m) break;
        if (r == 2) {
            for (int dz = -2; dz <= 2; ++dz) {
                const int z = cz + dz; if ((unsigned)z >= G_) continue;
                const bool zface = (dz == -2) | (dz == 2);
                for (int dy = -2; dy <= 2; ++dy) {
                    const int y = cy + dy; if ((unsigned)y >= G_) continue;
                    const int rb = (z * G_ + y) * G_ - cs0;
                    if (zface | (dy == -2) | (dy == 2)) {
                        const int x0 = max(cx - 2, 0), x1 = min(cx + 2, G_ - 1);
                        scan_lds(slab, scs[rb + x0] - start, scs[rb + x1 + 1] - start,
                                 s, px, py, pz, t);
                    } else {
                        const int xm = cx - 2, xp = cx + 2;
                        if (xm >= 0)
                            scan_lds(slab, scs[rb + xm] - start, scs[rb + xm + 1] - start,
                                     s, px, py, pz, t);
                        if (xp < G_)
                            scan_lds(slab, scs[rb + xp] - start, scs[rb + xp + 1] - start,
                                     s, px, py, pz, t);
                    }
                }
            }
        } else {
            for (int dz = -r; dz <= r; ++dz) {
                const int z = cz + dz; if ((unsigned)z >= G_) continue;
                const bool zface = (dz == -r) | (dz == r);
                for (int dy = -r; dy <= r; ++dy) {
                    const int y = cy + dy; if ((unsigned)y >= G_) continue;
                    const int rb = (z * G_ + y) * G_;
                    if (zface | (dy == -r) | (dy == r)) {
                        const int x0 = max(cx - r, 0), x1 = min(cx + r, G_ - 1);
                        scan_glb(sp, csg[rb + x0], csg[rb + x1 + 1], s, px, py, pz, t);
                    } else {
                        const int xm = cx - r, xp = cx + r;
                        if (xm >= 0) scan_glb(sp, csg[rb + xm], csg[rb + xm + 1], s, px, py, pz, t);
                        if (xp < G_) scan_glb(sp, csg[rb + xp], csg[rb + xp + 1], s, px, py, pz, t);
                    }
                }
            }
        }
        // Valid upper bound: union 8th <= min over the pair of per-lane 8th.
        float e = fminf(t[KNN_ - 1], __shfl_xor(t[KNN_ - 1], 1));
        m = fminf(m, e);
    }

    // Final exact top-8 of the 2 disjoint lane lists.
    merge_pair(t, 1);

    float tsum = 0.0f;
    if (s == 0) {
#pragma unroll
        for (int k = 0; k < KNN_; k++) {
            const float dm = fmaxf(t[k], 1e-12f);   // self: d2=0 -> dn=1e-6
            const float dn = sqrtf(dm);
            tsum += (RADIUS_ - dn) * __expf(-dm * INV_H2_);
        }
    }
#pragma unroll
    for (int off = 1; off < 64; off <<= 1) tsum += __shfl_xor(tsum, off);
    if ((tid & 63) == 0) atomicAdd(out, tsum * SCALE_);
}

extern "C" void kernel_launch(void* const* d_in, const int* in_sizes, int n_in,
                              void* d_out, int out_size, void* d_ws, size_t ws_size,
                              hipStream_t stream) {
    const float* pts = (const float*)d_in[0];
    float*       out = (float*)d_out;

    char* ws = (char*)d_ws;
    float4* sorted4   = (float4*)(ws);                            // 524288 B
    int*    counts    = (int*)(ws + 524288);                      //  27648 B
    int*    cellStart = (int*)(ws + 524288 + 27648);              //  27664 B
    int*    cursor    = (int*)(ws + 524288 + 27648 + 27664);      //  27648 B

    hipMemsetAsync(counts, 0, B_ * C_ * sizeof(int), stream);
    count_kernel  <<<B_ * N_ / 256, 256, 0, stream>>>(pts, counts, out);
    scan_kernel   <<<B_,            256, 0, stream>>>(counts, cellStart, cursor);
    scatter_kernel<<<B_ * N_ / 256, 256, 0, stream>>>(pts, cursor, sorted4);
    query_kernel  <<<B_ * N_ / 128, 256, 0, stream>>>(sorted4, cellStart, out);
}